// Round 7
// baseline (450.479 us; speedup 1.0000x reference)
//
#include <hip/hip_runtime.h>

// dv = (-v + segment_sum(w * relu(v[src]) * tp[ntype[src]], dst) + stim + Vrest) / tau
// N_NODES = 500000, N_EDGES = 16000000. edge_index flat: src=[0,E), dst=[E,2E).
//
// R1:  agent-scope fp32 atomics -> memory-side RMW wall -> 785us.
// R2:  counting sort, direct 4B random writes -> 489us scatter.
// R4:  LDS-staged bucket sort + coalesced bursts -> 241us scatter.
// R5:  1024-thr scatter + prefix-derived hist -> 188us scatter.
// R8:  private slices + lpref. scatter 144, total 420.8.
// R9:  bucket-major global sort (atomic cursor, contiguous accum read).
//      scatter 172, total flat 422.7 (accum was never the cost).
// R10: manual MLP hoist WITHIN a phase: 182. REGRESSION. Reverted.
// R11: BSHIFT 11 (2048-node buckets, nb=245): scatter 161, total 411.5.
// R12: dense copy-out (4-aligned runs, byte map): scatter 156.5.
// R13: CROSS-PHASE g[src] prefetch (issue in P1, consume in P2 across the
//      scan barriers): scatter 142.8, total 396.2. The working mechanism.
// R14: + w prefetch: 167.5. REGRESSION -- live state (gv16+wreg16+dreg16)
//      exceeded the 64-VGPR budget -> scratch spill (WRITE 68.6->111.5MB,
//      FETCH +23MB at pinned VGPR=32). Prefetch pays only in-register.
// Ledger: non-scatter floor ~253us (harness-fixed + accum ~25); all pipes
//      <20% busy in scatter -> barrier-lockstep latency-bound: 16-wave
//      blocks, only 2 independent barrier groups/CU.
// R15 (this): revert to R13 P1/P2 (gv only). GEOMETRY: 256-thr blocks,
//      GPB=768 (12 edges/thr unchanged per-thread work), LDS 19.3KB ->
//      8 blocks/CU x 4 waves = 32 waves in 8 independent barrier groups
//      (vs 2). Exact-length reservations (no global pad) so cap slack
//      survives 5209 blocks; copy-out masks the <=3-record boundary
//      granule with dword stores (global dwordx4 is dword-aligned-legal).
//      gcur strided 64B/bucket to dodge per-line RMW wall. Predict
//      scatter ~115-130, WRITE ~64.5MB. If >=143: per-thread chains are
//      the floor -> ceiling.

#define BSHIFT 11
#define BSIZE  2048              // nodes per bucket
#define NBMAX  256               // > nb = ceil(500000/2048) = 245; fits uint8 map
#define BTH    256               // scatter block threads (4 waves)
#define GPB    768               // int4 groups per scatter block = 3072 edges
#define EPB    (GPB * 4)         // 3072 records
#define EPBP   (EPB + 736)       // + per-bucket 4-alignment waste (<=735), 16B mult
#define MAPSZ  (EPBP / 4)        // uint4-granule -> bucket byte map
#define GSTRIDE 16               // gcur words per bucket (64B: one line each)
#define SPILL_CAP 131072

// pack: round-to-nearest on the stolen low bits, then steal 11 for local dst
__device__ __forceinline__ unsigned pack_rec(float x, int d) {
    return ((__float_as_uint(x) + (unsigned)(BSIZE >> 1)) & ~(unsigned)(BSIZE - 1)) |
           ((unsigned)d & (BSIZE - 1));
}

// ---------------- main path ----------------

__global__ void pre_g_kernel(const float* __restrict__ v,
                             const int* __restrict__ ntype,
                             const float* __restrict__ tp,
                             float* __restrict__ g,
                             unsigned* __restrict__ gcur,
                             int n, int nb) {
    int i = blockIdx.x * blockDim.x + threadIdx.x;
    if (i < n) {
        float x = v[i];
        x = x > 0.0f ? x : 0.0f;
        g[i] = x * tp[ntype[i]];
    }
    if (i < (nb + 1) * GSTRIDE) gcur[i] = 0u;  // bucket cursors (strided) + spill count
}

// grid = nblk, 256 threads (4 waves). Bins one 3072-edge chunk into
// 4-record-aligned per-bucket runs in LDS, reserves EXACT-length global
// space per bucket via strided atomic cursor, then copies out densely
// (thread-per-uint4 granule, masked boundary stores).
__global__ __launch_bounds__(BTH, 8)
void scatter_kernel(const int* __restrict__ src,
                    const int* __restrict__ dst,
                    const float* __restrict__ w,
                    const float* __restrict__ g,
                    unsigned* __restrict__ bucketbuf,
                    unsigned* __restrict__ gcur,
                    uint2* __restrict__ spill,
                    int G, int n_edges, int nblk, int nb, int cap) {
    __shared__ unsigned stage[EPBP];       // 14.9 KB
    __shared__ unsigned lstart[NBMAX];     // 4-aligned exclusive starts (1 KB)
    __shared__ unsigned lcur[NBMAX];       // working cursors            (1 KB)
    __shared__ unsigned gposs[NBMAX];      // global positions           (1 KB)
    __shared__ unsigned char qmap[MAPSZ];  // uint4-granule -> bucket    (952 B)
    __shared__ unsigned wsum[16];
    int blk = blockIdx.x, tid = threadIdx.x;
    int wid = tid >> 6, lane = tid & 63;
    bool last = (blk == nblk - 1);

    lcur[tid] = 0;
    __syncthreads();

    const int4*   s4 = (const int4*)src;
    const int4*   d4 = (const int4*)dst;
    const float4* w4 = (const float4*)w;
    int gstart = blk * GPB;
    int gend = gstart + GPB; if (gend > G) gend = G;
    bool full = (gend - gstart) == GPB;

    // pass 1 (R13 form): dst stream loads + g-gather ISSUE (held in regs
    // across the scan barriers), then local histogram. Scan drains latency.
    int4 dreg[3];
    float gv[12];
    if (full) {
        int i0 = gstart + tid;
        int4 dA = d4[i0], dB = d4[i0 + BTH], dC = d4[i0 + 2 * BTH];
        int4 sA = s4[i0], sB = s4[i0 + BTH], sC = s4[i0 + 2 * BTH];
        gv[0] = g[sA.x]; gv[1] = g[sA.y]; gv[2]  = g[sA.z]; gv[3]  = g[sA.w];
        gv[4] = g[sB.x]; gv[5] = g[sB.y]; gv[6]  = g[sB.z]; gv[7]  = g[sB.w];
        gv[8] = g[sC.x]; gv[9] = g[sC.y]; gv[10] = g[sC.z]; gv[11] = g[sC.w];
        dreg[0] = dA; dreg[1] = dB; dreg[2] = dC;
        atomicAdd(&lcur[((unsigned)dA.x) >> BSHIFT], 1u);
        atomicAdd(&lcur[((unsigned)dA.y) >> BSHIFT], 1u);
        atomicAdd(&lcur[((unsigned)dA.z) >> BSHIFT], 1u);
        atomicAdd(&lcur[((unsigned)dA.w) >> BSHIFT], 1u);
        atomicAdd(&lcur[((unsigned)dB.x) >> BSHIFT], 1u);
        atomicAdd(&lcur[((unsigned)dB.y) >> BSHIFT], 1u);
        atomicAdd(&lcur[((unsigned)dB.z) >> BSHIFT], 1u);
        atomicAdd(&lcur[((unsigned)dB.w) >> BSHIFT], 1u);
        atomicAdd(&lcur[((unsigned)dC.x) >> BSHIFT], 1u);
        atomicAdd(&lcur[((unsigned)dC.y) >> BSHIFT], 1u);
        atomicAdd(&lcur[((unsigned)dC.z) >> BSHIFT], 1u);
        atomicAdd(&lcur[((unsigned)dC.w) >> BSHIFT], 1u);
    } else {
        #pragma unroll
        for (int k = 0; k < 3; k++) {
            int i = gstart + tid + k * BTH;
            if (i < gend) {
                int4 d = d4[i];
                dreg[k] = d;
                atomicAdd(&lcur[((unsigned)d.x) >> BSHIFT], 1u);
                atomicAdd(&lcur[((unsigned)d.y) >> BSHIFT], 1u);
                atomicAdd(&lcur[((unsigned)d.z) >> BSHIFT], 1u);
                atomicAdd(&lcur[((unsigned)d.w) >> BSHIFT], 1u);
            }
        }
    }
    if (last) {
        for (int i = G * 4 + tid; i < n_edges; i += BTH)
            atomicAdd(&lcur[((unsigned)dst[i]) >> BSHIFT], 1u);
    }
    __syncthreads();

    // exclusive scan over 256 entries of the 4-ALIGNED counts (LDS regions
    // 16B-aligned for b128 reads). 4 waves hold counts; shfl scan +
    // cross-wave scan of partials. (Also hides the gv[] gather latency.)
    unsigned rawc = lcur[tid];
    unsigned cntv = (rawc + 3u) & ~3u;
    unsigned inc = cntv;
    #pragma unroll
    for (int o = 1; o < 64; o <<= 1) {
        unsigned t = __shfl_up(inc, o, 64);
        if (lane >= o) inc += t;
    }
    if (lane == 63) wsum[wid] = inc;
    __syncthreads();
    if (tid < 64) {
        unsigned x = (lane < 4) ? wsum[lane] : 0u;
        unsigned xi = x;
        #pragma unroll
        for (int o = 1; o < 4; o <<= 1) {
            unsigned t = __shfl_up(xi, o, 64);
            if (lane >= o) xi += t;
        }
        if (lane < 4) wsum[lane] = xi - x;   // exclusive wave offsets
    }
    __syncthreads();
    {
        unsigned excl = inc - cntv + wsum[wid];
        lstart[tid] = excl;       // 4-aligned
        lcur[tid] = excl;
    }
    __syncthreads();

    // pass 2: bin packed records (g in registers; w is a coalesced stream).
    if (full) {
        int i0 = gstart + tid;
        #pragma unroll
        for (int k = 0; k < 3; k++) {
            float4 wv = w4[i0 + k * BTH];
            int4 d = dreg[k];
            unsigned pos;
            pos = atomicAdd(&lcur[((unsigned)d.x) >> BSHIFT], 1u);
            stage[pos] = pack_rec(wv.x * gv[4 * k + 0], d.x);
            pos = atomicAdd(&lcur[((unsigned)d.y) >> BSHIFT], 1u);
            stage[pos] = pack_rec(wv.y * gv[4 * k + 1], d.y);
            pos = atomicAdd(&lcur[((unsigned)d.z) >> BSHIFT], 1u);
            stage[pos] = pack_rec(wv.z * gv[4 * k + 2], d.z);
            pos = atomicAdd(&lcur[((unsigned)d.w) >> BSHIFT], 1u);
            stage[pos] = pack_rec(wv.w * gv[4 * k + 3], d.w);
        }
    } else {
        #pragma unroll
        for (int k = 0; k < 3; k++) {
            int i = gstart + tid + k * BTH;
            if (i < gend) {
                int4 s = s4[i]; float4 wv = w4[i]; int4 d = dreg[k];
                unsigned pos;
                pos = atomicAdd(&lcur[((unsigned)d.x) >> BSHIFT], 1u);
                stage[pos] = pack_rec(wv.x * g[s.x], d.x);
                pos = atomicAdd(&lcur[((unsigned)d.y) >> BSHIFT], 1u);
                stage[pos] = pack_rec(wv.y * g[s.y], d.y);
                pos = atomicAdd(&lcur[((unsigned)d.z) >> BSHIFT], 1u);
                stage[pos] = pack_rec(wv.z * g[s.z], d.z);
                pos = atomicAdd(&lcur[((unsigned)d.w) >> BSHIFT], 1u);
                stage[pos] = pack_rec(wv.w * g[s.w], d.w);
            }
        }
    }
    if (last) {
        for (int i = G * 4 + tid; i < n_edges; i += BTH) {
            int dd = dst[i];
            unsigned b = ((unsigned)dd) >> BSHIFT;
            unsigned pos = atomicAdd(&lcur[b], 1u);
            stage[pos] = pack_rec(w[i] * g[src[i]], dd);
        }
    }
    __syncthreads();

    // reserve (EXACT length, strided cursor line per bucket) + q->bucket map
    if (tid < nb) {
        unsigned st  = lstart[tid];
        unsigned len = lcur[tid] - st;
        unsigned p = 0u;
        if (len) {
            p = atomicAdd(&gcur[tid * GSTRIDE], len);
            if (p + len > (unsigned)cap) {           // many-sigma event: spill run
                atomicSub(&gcur[tid * GSTRIDE], len);
                unsigned sp = atomicAdd(&gcur[nb * GSTRIDE], len);
                p = 0x80000000u | sp;
            }
            for (unsigned q = st >> 2; q < (st + len + 3u) >> 2; q++)
                qmap[q] = (unsigned char)tid;
        }
        gposs[tid] = p;
    }
    __syncthreads();

    // dense copy-out: thread per uint4 granule. Full granules: one
    // ds_read_b128 + dwordx4 store (dword-aligned dest is legal). Boundary
    // granule of each run (<=3 records): masked dword stores.
    unsigned total4 = lstart[nb] >> 2;     // aligned total (index nb = 245)
    const uint4* st4 = (const uint4*)stage;
    for (unsigned q = tid; q < total4; q += BTH) {
        unsigned b = qmap[q];
        unsigned st = lstart[b];
        unsigned p = gposs[b];
        unsigned roff = (q << 2) - st;
        unsigned len = lcur[b] - st;
        unsigned nvalid = len - roff; if (nvalid > 4u) nvalid = 4u;
        if (p & 0x80000000u) {
            unsigned sp = (p & 0x7FFFFFFFu) + roff;
            for (unsigned t = 0; t < nvalid; t++) {
                if (sp + t < SPILL_CAP) {
                    unsigned u = stage[(q << 2) + t];
                    spill[sp + t] = make_uint2((b << BSHIFT) | (u & (BSIZE - 1u)),
                                               u & ~(unsigned)(BSIZE - 1));
                }
            }
        } else {
            unsigned* dp = bucketbuf + (size_t)b * (unsigned)cap + p + roff;
            if (nvalid == 4u) {
                *(uint4*)dp = st4[q];
            } else {
                for (unsigned t = 0; t < nvalid; t++)
                    dp[t] = stage[(q << 2) + t];
            }
        }
    }
}

// grid = nb, 1024 threads. One contiguous region per bucket (exact count);
// acc[2048] in LDS, two output nodes per thread. Epilogue streams issued
// before the record loop (latency hidden under it).
__global__ __launch_bounds__(1024, 2)
void accum_kernel(const unsigned* __restrict__ bucketbuf,
                  const unsigned* __restrict__ gcur,
                  const uint2* __restrict__ spill,
                  const float* __restrict__ v,
                  const float* __restrict__ stim,
                  const float* __restrict__ vrest,
                  const float* __restrict__ tau,
                  float* __restrict__ out,
                  int n_nodes, int nb, int cap) {
    __shared__ float acc[BSIZE];
    int b = blockIdx.x, tid = threadIdx.x;
    acc[tid] = 0.0f;
    acc[tid + 1024] = 0.0f;
    __syncthreads();

    // issue epilogue streams early (held across the record loop)
    int i0 = (b << BSHIFT) + tid;
    int i1 = i0 + 1024;
    bool ok0 = i0 < n_nodes, ok1 = i1 < n_nodes;
    float v0 = 0.f, s0 = 0.f, r0 = 0.f, t0 = 1.f;
    float v1 = 0.f, s1 = 0.f, r1 = 0.f, t1 = 1.f;
    if (ok0) { v0 = v[i0]; s0 = stim[i0]; r0 = vrest[i0]; t0 = tau[i0]; }
    if (ok1) { v1 = v[i1]; s1 = stim[i1]; r1 = vrest[i1]; t1 = tau[i1]; }

    unsigned cnt = gcur[b * GSTRIDE];
    if (cnt > (unsigned)cap) cnt = (unsigned)cap;
    const unsigned* base = bucketbuf + (size_t)b * (unsigned)cap;
    const uint4* b4 = (const uint4*)base;
    unsigned nq = cnt >> 2;
    for (unsigned i = tid; i < nq; i += 1024) {
        uint4 u = b4[i];
        atomicAdd(&acc[u.x & (BSIZE - 1u)], __uint_as_float(u.x & ~(unsigned)(BSIZE - 1)));
        atomicAdd(&acc[u.y & (BSIZE - 1u)], __uint_as_float(u.y & ~(unsigned)(BSIZE - 1)));
        atomicAdd(&acc[u.z & (BSIZE - 1u)], __uint_as_float(u.z & ~(unsigned)(BSIZE - 1)));
        atomicAdd(&acc[u.w & (BSIZE - 1u)], __uint_as_float(u.w & ~(unsigned)(BSIZE - 1)));
    }
    for (unsigned i = (nq << 2) + tid; i < cnt; i += 1024) {
        unsigned u = base[i];
        atomicAdd(&acc[u & (BSIZE - 1u)], __uint_as_float(u & ~(unsigned)(BSIZE - 1)));
    }

    unsigned sn = gcur[nb * GSTRIDE];     // spill count: 0 in practice (1 load)
    if (sn) {
        if (sn > SPILL_CAP) sn = SPILL_CAP;
        for (unsigned i = tid; i < sn; i += 1024) {
            uint2 e = spill[i];
            if ((int)(e.x >> BSHIFT) == b)
                atomicAdd(&acc[e.x & (BSIZE - 1u)], __uint_as_float(e.y));
        }
    }
    __syncthreads();

    if (ok0) out[i0] = (-v0 + acc[tid] + s0 + r0) / t0;
    if (ok1) out[i1] = (-v1 + acc[tid + 1024] + s1 + r1) / t1;
}

// ---------------- fallback (agent-scope atomics, always correct) ----------------

__global__ void node_pre_kernel(const float* __restrict__ v,
                                const int* __restrict__ ntype,
                                const float* __restrict__ tp,
                                float* __restrict__ g,
                                float* __restrict__ msg, int n) {
    int i = blockIdx.x * blockDim.x + threadIdx.x;
    if (i < n) {
        float x = v[i];
        x = x > 0.0f ? x : 0.0f;
        g[i] = x * tp[ntype[i]];
        msg[i] = 0.0f;
    }
}

__global__ void edge_scatter_kernel(const int* __restrict__ src,
                                    const int* __restrict__ dst,
                                    const float* __restrict__ w,
                                    const float* __restrict__ g,
                                    float* __restrict__ msg, int n_vec) {
    int i = blockIdx.x * blockDim.x + threadIdx.x;
    if (i < n_vec) {
        int4 s = ((const int4*)src)[i];
        int4 d = ((const int4*)dst)[i];
        float4 wv = ((const float4*)w)[i];
        atomicAdd(&msg[d.x], wv.x * g[s.x]);
        atomicAdd(&msg[d.y], wv.y * g[s.y]);
        atomicAdd(&msg[d.z], wv.z * g[s.z]);
        atomicAdd(&msg[d.w], wv.w * g[s.w]);
    }
}

__global__ void edge_scatter_tail(const int* __restrict__ src,
                                  const int* __restrict__ dst,
                                  const float* __restrict__ w,
                                  const float* __restrict__ g,
                                  float* __restrict__ msg,
                                  int start, int n_edges) {
    int i = start + blockIdx.x * blockDim.x + threadIdx.x;
    if (i < n_edges) atomicAdd(&msg[dst[i]], w[i] * g[src[i]]);
}

__global__ void node_post_kernel(const float* __restrict__ v,
                                 const float* __restrict__ msg,
                                 const float* __restrict__ stim,
                                 const float* __restrict__ vrest,
                                 const float* __restrict__ tau,
                                 float* __restrict__ out, int n) {
    int i = blockIdx.x * blockDim.x + threadIdx.x;
    if (i < n)
        out[i] = (-v[i] + msg[i] + stim[i] + vrest[i]) / tau[i];
}

// ---------------- launch ----------------

extern "C" void kernel_launch(void* const* d_in, const int* in_sizes, int n_in,
                              void* d_out, int out_size, void* d_ws, size_t ws_size,
                              hipStream_t stream) {
    const float* voltage  = (const float*)d_in[0];
    const float* stimulus = (const float*)d_in[1];
    const int*   ntype    = (const int*)d_in[2];
    const int*   edge_idx = (const int*)d_in[3];
    const float* w        = (const float*)d_in[4];
    const float* vrest    = (const float*)d_in[5];
    const float* tau      = (const float*)d_in[6];
    const float* tp       = (const float*)d_in[7];
    float* out = (float*)d_out;

    const int n_nodes = in_sizes[0];
    const int n_edges = in_sizes[4];
    const int* src = edge_idx;
    const int* dst = edge_idx + n_edges;

    const int B = 256;
    const int G = n_edges / 4;
    int nblk = (G + GPB - 1) / GPB;
    if (nblk < 1) nblk = 1;
    const int nb = (n_nodes + BSIZE - 1) / BSIZE;

    auto align256 = [](size_t x) { return (x + 255) & ~(size_t)255; };

    // per-bucket capacity: mean load (65306) + slack. Reservations are
    // exact-length now (no pad), so slack only covers binomial spread
    // (sigma ~= 255): 2048 = 8 sigma. Pick the largest slack that fits.
    int base_cap = (int)(((long long)n_edges * BSIZE) / (long long)(n_nodes > 0 ? n_nodes : 1));
    const int slacks[3] = {4096, 3072, 2048};
    int cap = 0;
    size_t g_off = 0, gcur_off = 0, spill_off = 0, bb_off = 0, need = (size_t)-1;
    for (int si = 0; si < 3; si++) {
        int c = (base_cap + slacks[si] + 3) & ~3;
        size_t go  = 0;
        size_t gc  = align256(go + (size_t)n_nodes * 4);
        size_t sp  = align256(gc + (size_t)(nb + 1) * GSTRIDE * 4);
        size_t bb  = align256(sp + (size_t)SPILL_CAP * 8);
        size_t nd  = align256(bb + (size_t)nb * (size_t)c * 4);
        if (nd <= ws_size) {
            cap = c; g_off = go; gcur_off = gc; spill_off = sp; bb_off = bb; need = nd;
            break;
        }
    }

    if (nb < NBMAX && cap > 0 && need <= ws_size) {
        float*    g         = (float*)((char*)d_ws + g_off);
        unsigned* gcur      = (unsigned*)((char*)d_ws + gcur_off);
        uint2*    spill     = (uint2*)((char*)d_ws + spill_off);
        unsigned* bucketbuf = (unsigned*)((char*)d_ws + bb_off);

        pre_g_kernel<<<(n_nodes + B - 1) / B, B, 0, stream>>>(
            voltage, ntype, tp, g, gcur, n_nodes, nb);
        scatter_kernel<<<nblk, BTH, 0, stream>>>(
            src, dst, w, g, bucketbuf, gcur, spill, G, n_edges, nblk, nb, cap);
        accum_kernel<<<nb, 1024, 0, stream>>>(
            bucketbuf, gcur, spill, voltage, stimulus, vrest, tau, out,
            n_nodes, nb, cap);
    } else {
        float* g   = (float*)d_ws;
        float* msg = (float*)d_ws + n_nodes;
        node_pre_kernel<<<(n_nodes + B - 1) / B, B, 0, stream>>>(
            voltage, ntype, tp, g, msg, n_nodes);
        if (G > 0)
            edge_scatter_kernel<<<(G + B - 1) / B, B, 0, stream>>>(
                src, dst, w, g, msg, G);
        if (G * 4 < n_edges) {
            int rem = n_edges - G * 4;
            edge_scatter_tail<<<(rem + B - 1) / B, B, 0, stream>>>(
                src, dst, w, g, msg, G * 4, n_edges);
        }
        node_post_kernel<<<(n_nodes + B - 1) / B, B, 0, stream>>>(
            voltage, msg, stimulus, vrest, tau, out, n_nodes);
    }
}

// Round 8
// 395.645 us; speedup vs baseline: 1.1386x; 1.1386x over previous
//
#include <hip/hip_runtime.h>

// dv = (-v + segment_sum(w * relu(v[src]) * tp[ntype[src]], dst) + stim + Vrest) / tau
// N_NODES = 500000, N_EDGES = 16000000. edge_index flat: src=[0,E), dst=[E,2E).
//
// R1:  agent-scope fp32 atomics -> memory-side RMW wall -> 785us.
// R2:  counting sort, direct 4B random writes -> 489us scatter.
// R4:  LDS-staged bucket sort + coalesced bursts -> 241us scatter.
// R5:  1024-thr scatter + prefix-derived hist -> 188us scatter.
// R8:  private slices + lpref. scatter 144, total 420.8.
// R9:  bucket-major global sort (atomic cursor, contiguous accum read).
//      scatter 172, total flat 422.7 (accum was never the cost).
// R10: manual MLP hoist WITHIN a phase: 182. REGRESSION. Reverted.
// R11: BSHIFT 11 (2048-node buckets, nb=245): scatter 161, total 411.5.
// R12: dense copy-out (4-aligned runs, byte map): scatter 156.5.
// R13: CROSS-PHASE g[src] prefetch (issue in P1, consume in P2 across the
//      scan barriers): scatter 142.8, total 396.2. BEST.
// R14: + w prefetch: 167.5. REGRESSION -- live state exceeded the 64-VGPR
//      residency budget -> scratch spill (WRITE 68.6->111.5MB). Lesson:
//      cross-phase prefetch pays only while it stays in registers.
// R15: 256-thr blocks (8 barrier groups/CU): 197. REGRESSION -- run length
//      = block_edges/nb fell to 12.5 records (~50B); 1.28M scattered
//      partial-line writes -> WRITE 139MB (~2x amp). Lesson: bucket-major
//      copy-out requires large blocks (runs >= ~64 records).
// Ledger: non-scatter component invariant 250-253us across R9-R15
//      (harness-fixed + accum ~25us). All structural levers on the scatter
//      core probed: within-phase reorder (x), bigger hold-set (x), finer
//      blocks (x). R16: restore R13 verbatim = structural floor
//      (~253 fixed + ~143 scatter).

#define BSHIFT 11
#define BSIZE  2048              // nodes per bucket
#define NBMAX  256               // > nb = ceil(500000/2048) = 245; fits uint8 map
#define GPB    4096              // int4 groups per scatter block = 16384 edges
#define EPB    (GPB * 4)
#define EPBP   (EPB + 1024)      // stage + per-bucket 4-alignment padding (<=735)
#define MAPSZ  (EPBP / 4)        // uint4-granule -> bucket byte map
#define SPILL_CAP 131072

// pack: round-to-nearest on the stolen low bits, then steal 11 for local dst
__device__ __forceinline__ unsigned pack_rec(float x, int d) {
    return ((__float_as_uint(x) + (unsigned)(BSIZE >> 1)) & ~(unsigned)(BSIZE - 1)) |
           ((unsigned)d & (BSIZE - 1));
}

// ---------------- main path ----------------

__global__ void pre_g_kernel(const float* __restrict__ v,
                             const int* __restrict__ ntype,
                             const float* __restrict__ tp,
                             float* __restrict__ g,
                             unsigned* __restrict__ gcur,
                             int n, int nb) {
    int i = blockIdx.x * blockDim.x + threadIdx.x;
    if (i < n) {
        float x = v[i];
        x = x > 0.0f ? x : 0.0f;
        g[i] = x * tp[ntype[i]];
    }
    if (i <= nb) gcur[i] = 0u;   // gcur[0..nb-1] = bucket cursors, gcur[nb] = spill count
}

// grid = nblk, 1024 threads. Bins one 16K-edge chunk into 4-record-aligned
// per-bucket runs in LDS, reserves global per-bucket space via atomic
// cursor, then copies out densely (thread-per-uint4, byte map).
__global__ __launch_bounds__(1024, 8)
void scatter_kernel(const int* __restrict__ src,
                    const int* __restrict__ dst,
                    const float* __restrict__ w,
                    const float* __restrict__ g,
                    unsigned* __restrict__ bucketbuf,
                    unsigned* __restrict__ gcur,
                    uint2* __restrict__ spill,
                    int G, int n_edges, int nblk, int nb, int cap) {
    __shared__ unsigned stage[EPBP];       // 69.6 KB
    __shared__ unsigned lstart[NBMAX];     // 4-aligned exclusive starts (1 KB)
    __shared__ unsigned lcur[NBMAX];       // working cursors            (1 KB)
    __shared__ unsigned gposs[NBMAX];      // global positions           (1 KB)
    __shared__ unsigned char qmap[MAPSZ];  // uint4-granule -> bucket    (4.3 KB)
    __shared__ unsigned wsum[16];
    int blk = blockIdx.x, tid = threadIdx.x;
    int wid = tid >> 6, lane = tid & 63;
    bool last = (blk == nblk - 1);

    if (tid < NBMAX) lcur[tid] = 0;
    __syncthreads();

    const int4*   s4 = (const int4*)src;
    const int4*   d4 = (const int4*)dst;
    const float4* w4 = (const float4*)w;
    int gstart = blk * GPB;
    int gend = gstart + GPB; if (gend > G) gend = G;
    bool full = (gend - gstart) == GPB;

    // pass 1: dst loads + g-gather ISSUE (prefetch held across the scan),
    // then local histogram. The gather latency drains during the scan phase.
    int4 dreg[4];
    float gv[16];
    if (full) {
        int i0 = gstart + tid;
        int4 dA = d4[i0], dB = d4[i0 + 1024], dC = d4[i0 + 2048], dD = d4[i0 + 3072];
        int4 sA = s4[i0], sB = s4[i0 + 1024], sC = s4[i0 + 2048], sD = s4[i0 + 3072];
        gv[0]  = g[sA.x]; gv[1]  = g[sA.y]; gv[2]  = g[sA.z]; gv[3]  = g[sA.w];
        gv[4]  = g[sB.x]; gv[5]  = g[sB.y]; gv[6]  = g[sB.z]; gv[7]  = g[sB.w];
        gv[8]  = g[sC.x]; gv[9]  = g[sC.y]; gv[10] = g[sC.z]; gv[11] = g[sC.w];
        gv[12] = g[sD.x]; gv[13] = g[sD.y]; gv[14] = g[sD.z]; gv[15] = g[sD.w];
        dreg[0] = dA; dreg[1] = dB; dreg[2] = dC; dreg[3] = dD;
        atomicAdd(&lcur[((unsigned)dA.x) >> BSHIFT], 1u);
        atomicAdd(&lcur[((unsigned)dA.y) >> BSHIFT], 1u);
        atomicAdd(&lcur[((unsigned)dA.z) >> BSHIFT], 1u);
        atomicAdd(&lcur[((unsigned)dA.w) >> BSHIFT], 1u);
        atomicAdd(&lcur[((unsigned)dB.x) >> BSHIFT], 1u);
        atomicAdd(&lcur[((unsigned)dB.y) >> BSHIFT], 1u);
        atomicAdd(&lcur[((unsigned)dB.z) >> BSHIFT], 1u);
        atomicAdd(&lcur[((unsigned)dB.w) >> BSHIFT], 1u);
        atomicAdd(&lcur[((unsigned)dC.x) >> BSHIFT], 1u);
        atomicAdd(&lcur[((unsigned)dC.y) >> BSHIFT], 1u);
        atomicAdd(&lcur[((unsigned)dC.z) >> BSHIFT], 1u);
        atomicAdd(&lcur[((unsigned)dC.w) >> BSHIFT], 1u);
        atomicAdd(&lcur[((unsigned)dD.x) >> BSHIFT], 1u);
        atomicAdd(&lcur[((unsigned)dD.y) >> BSHIFT], 1u);
        atomicAdd(&lcur[((unsigned)dD.z) >> BSHIFT], 1u);
        atomicAdd(&lcur[((unsigned)dD.w) >> BSHIFT], 1u);
    } else {
        #pragma unroll
        for (int k = 0; k < 4; k++) {
            int i = gstart + tid + k * 1024;
            if (i < gend) {
                int4 d = d4[i];
                dreg[k] = d;
                atomicAdd(&lcur[((unsigned)d.x) >> BSHIFT], 1u);
                atomicAdd(&lcur[((unsigned)d.y) >> BSHIFT], 1u);
                atomicAdd(&lcur[((unsigned)d.z) >> BSHIFT], 1u);
                atomicAdd(&lcur[((unsigned)d.w) >> BSHIFT], 1u);
            }
        }
    }
    if (last) {
        for (int i = G * 4 + tid; i < n_edges; i += 1024)
            atomicAdd(&lcur[((unsigned)dst[i]) >> BSHIFT], 1u);
    }
    __syncthreads();

    // exclusive scan over NBMAX=256 entries of the 4-ALIGNED counts, so
    // every bucket's stage region starts on a uint4 boundary. (This phase
    // also hides the gv[] gather latency issued above.)
    unsigned rawc = (tid < NBMAX) ? lcur[tid] : 0u;
    unsigned cntv = (rawc + 3u) & ~3u;
    unsigned inc = cntv;
    #pragma unroll
    for (int o = 1; o < 64; o <<= 1) {
        unsigned t = __shfl_up(inc, o, 64);
        if (lane >= o) inc += t;
    }
    if (lane == 63) wsum[wid] = inc;
    __syncthreads();
    if (tid < 64) {
        unsigned x = (lane < 16) ? wsum[lane] : 0u;
        unsigned xi = x;
        #pragma unroll
        for (int o = 1; o < 16; o <<= 1) {
            unsigned t = __shfl_up(xi, o, 64);
            if (lane >= o) xi += t;
        }
        if (lane < 16) wsum[lane] = xi - x;   // exclusive wave offsets
    }
    __syncthreads();
    if (tid < NBMAX) {
        unsigned excl = inc - cntv + wsum[wid];
        lstart[tid] = excl;       // 4-aligned
        lcur[tid] = excl;
    }
    __syncthreads();

    // pass 2: bin packed records. Full path: g in registers, w as a cheap
    // coalesced stream (NOT prefetched -- R14 showed the extra hold-set
    // spills past the 64-VGPR residency budget).
    if (full) {
        int i0 = gstart + tid;
        #pragma unroll
        for (int k = 0; k < 4; k++) {
            float4 wv = w4[i0 + k * 1024];
            int4 d = dreg[k];
            unsigned pos;
            pos = atomicAdd(&lcur[((unsigned)d.x) >> BSHIFT], 1u);
            stage[pos] = pack_rec(wv.x * gv[4 * k + 0], d.x);
            pos = atomicAdd(&lcur[((unsigned)d.y) >> BSHIFT], 1u);
            stage[pos] = pack_rec(wv.y * gv[4 * k + 1], d.y);
            pos = atomicAdd(&lcur[((unsigned)d.z) >> BSHIFT], 1u);
            stage[pos] = pack_rec(wv.z * gv[4 * k + 2], d.z);
            pos = atomicAdd(&lcur[((unsigned)d.w) >> BSHIFT], 1u);
            stage[pos] = pack_rec(wv.w * gv[4 * k + 3], d.w);
        }
    } else {
        #pragma unroll
        for (int k = 0; k < 4; k++) {
            int i = gstart + tid + k * 1024;
            if (i < gend) {
                int4 s = s4[i]; float4 wv = w4[i]; int4 d = dreg[k];
                unsigned pos;
                pos = atomicAdd(&lcur[((unsigned)d.x) >> BSHIFT], 1u);
                stage[pos] = pack_rec(wv.x * g[s.x], d.x);
                pos = atomicAdd(&lcur[((unsigned)d.y) >> BSHIFT], 1u);
                stage[pos] = pack_rec(wv.y * g[s.y], d.y);
                pos = atomicAdd(&lcur[((unsigned)d.z) >> BSHIFT], 1u);
                stage[pos] = pack_rec(wv.z * g[s.z], d.z);
                pos = atomicAdd(&lcur[((unsigned)d.w) >> BSHIFT], 1u);
                stage[pos] = pack_rec(wv.w * g[s.w], d.w);
            }
        }
    }
    if (last) {
        for (int i = G * 4 + tid; i < n_edges; i += 1024) {
            int dd = dst[i];
            unsigned b = ((unsigned)dd) >> BSHIFT;
            unsigned pos = atomicAdd(&lcur[b], 1u);
            stage[pos] = pack_rec(w[i] * g[src[i]], dd);
        }
    }
    __syncthreads();

    // reserve + pad + map phase (one thread per bucket)
    if (tid < nb) {
        unsigned st   = lstart[tid];
        unsigned end  = lcur[tid];
        unsigned len  = end - st;
        unsigned len4 = (len + 3u) & ~3u;
        unsigned p = 0u;
        if (len) {
            p = atomicAdd(&gcur[tid], len4);
            if (p + len4 > (unsigned)cap) {          // many-sigma event: spill run
                atomicSub(&gcur[tid], len4);
                unsigned sp = atomicAdd(&gcur[nb], len4);
                p = 0x80000000u | sp;
            }
            for (unsigned j = end; j < st + len4; j++)
                stage[j] = j & (unsigned)(BSIZE - 1);   // value +0.0, spread idx
            for (unsigned q = st >> 2; q < (st + len4) >> 2; q++)
                qmap[q] = (unsigned char)tid;
        }
        gposs[tid] = p;
    }
    __syncthreads();

    // dense copy-out: thread per uint4 granule, full lane utilization.
    unsigned total4 = lstart[nb] >> 2;     // scan of aligned counts at index nb
    const uint4* st4 = (const uint4*)stage;
    for (unsigned q = tid; q < total4; q += 1024) {
        unsigned b = qmap[q];
        unsigned p = gposs[b];
        unsigned roff = (q << 2) - lstart[b];
        if (p & 0x80000000u) {
            unsigned sp = (p & 0x7FFFFFFFu) + roff;
            #pragma unroll
            for (int t = 0; t < 4; t++) {
                if (sp + t < SPILL_CAP) {
                    unsigned u = stage[(q << 2) + t];
                    spill[sp + t] = make_uint2((b << BSHIFT) | (u & (BSIZE - 1u)),
                                               u & ~(unsigned)(BSIZE - 1));
                }
            }
        } else {
            uint4* dp4 = (uint4*)(bucketbuf + (size_t)b * (unsigned)cap + p + roff);
            *dp4 = st4[q];
        }
    }
}

// grid = nb, 1024 threads. One contiguous uint4-coalesced region per bucket;
// acc[2048] in LDS, two output nodes per thread.
__global__ __launch_bounds__(1024, 2)
void accum_kernel(const unsigned* __restrict__ bucketbuf,
                  const unsigned* __restrict__ gcur,
                  const uint2* __restrict__ spill,
                  const float* __restrict__ v,
                  const float* __restrict__ stim,
                  const float* __restrict__ vrest,
                  const float* __restrict__ tau,
                  float* __restrict__ out,
                  int n_nodes, int nb, int cap) {
    __shared__ float acc[BSIZE];
    int b = blockIdx.x, tid = threadIdx.x;
    acc[tid] = 0.0f;
    acc[tid + 1024] = 0.0f;
    __syncthreads();

    unsigned cnt = gcur[b];
    if (cnt > (unsigned)cap) cnt = (unsigned)cap;
    const unsigned* base = bucketbuf + (size_t)b * (unsigned)cap;
    const uint4* b4 = (const uint4*)base;
    unsigned nq = cnt >> 2;
    for (unsigned i = tid; i < nq; i += 1024) {
        uint4 u = b4[i];
        atomicAdd(&acc[u.x & (BSIZE - 1u)], __uint_as_float(u.x & ~(unsigned)(BSIZE - 1)));
        atomicAdd(&acc[u.y & (BSIZE - 1u)], __uint_as_float(u.y & ~(unsigned)(BSIZE - 1)));
        atomicAdd(&acc[u.z & (BSIZE - 1u)], __uint_as_float(u.z & ~(unsigned)(BSIZE - 1)));
        atomicAdd(&acc[u.w & (BSIZE - 1u)], __uint_as_float(u.w & ~(unsigned)(BSIZE - 1)));
    }
    for (unsigned i = (nq << 2) + tid; i < cnt; i += 1024) {
        unsigned u = base[i];
        atomicAdd(&acc[u & (BSIZE - 1u)], __uint_as_float(u & ~(unsigned)(BSIZE - 1)));
    }

    unsigned sn = gcur[nb];               // spill count: 0 in practice (1 load)
    if (sn) {
        if (sn > SPILL_CAP) sn = SPILL_CAP;
        for (unsigned i = tid; i < sn; i += 1024) {
            uint2 e = spill[i];
            if ((int)(e.x >> BSHIFT) == b)
                atomicAdd(&acc[e.x & (BSIZE - 1u)], __uint_as_float(e.y));
        }
    }
    __syncthreads();

    int i0 = (b << BSHIFT) + tid;
    if (i0 < n_nodes)
        out[i0] = (-v[i0] + acc[tid] + stim[i0] + vrest[i0]) / tau[i0];
    int i1 = i0 + 1024;
    if (i1 < n_nodes)
        out[i1] = (-v[i1] + acc[tid + 1024] + stim[i1] + vrest[i1]) / tau[i1];
}

// ---------------- fallback (agent-scope atomics, always correct) ----------------

__global__ void node_pre_kernel(const float* __restrict__ v,
                                const int* __restrict__ ntype,
                                const float* __restrict__ tp,
                                float* __restrict__ g,
                                float* __restrict__ msg, int n) {
    int i = blockIdx.x * blockDim.x + threadIdx.x;
    if (i < n) {
        float x = v[i];
        x = x > 0.0f ? x : 0.0f;
        g[i] = x * tp[ntype[i]];
        msg[i] = 0.0f;
    }
}

__global__ void edge_scatter_kernel(const int* __restrict__ src,
                                    const int* __restrict__ dst,
                                    const float* __restrict__ w,
                                    const float* __restrict__ g,
                                    float* __restrict__ msg, int n_vec) {
    int i = blockIdx.x * blockDim.x + threadIdx.x;
    if (i < n_vec) {
        int4 s = ((const int4*)src)[i];
        int4 d = ((const int4*)dst)[i];
        float4 wv = ((const float4*)w)[i];
        atomicAdd(&msg[d.x], wv.x * g[s.x]);
        atomicAdd(&msg[d.y], wv.y * g[s.y]);
        atomicAdd(&msg[d.z], wv.z * g[s.z]);
        atomicAdd(&msg[d.w], wv.w * g[s.w]);
    }
}

__global__ void edge_scatter_tail(const int* __restrict__ src,
                                  const int* __restrict__ dst,
                                  const float* __restrict__ w,
                                  const float* __restrict__ g,
                                  float* __restrict__ msg,
                                  int start, int n_edges) {
    int i = start + blockIdx.x * blockDim.x + threadIdx.x;
    if (i < n_edges) atomicAdd(&msg[dst[i]], w[i] * g[src[i]]);
}

__global__ void node_post_kernel(const float* __restrict__ v,
                                 const float* __restrict__ msg,
                                 const float* __restrict__ stim,
                                 const float* __restrict__ vrest,
                                 const float* __restrict__ tau,
                                 float* __restrict__ out, int n) {
    int i = blockIdx.x * blockDim.x + threadIdx.x;
    if (i < n)
        out[i] = (-v[i] + msg[i] + stim[i] + vrest[i]) / tau[i];
}

// ---------------- launch ----------------

extern "C" void kernel_launch(void* const* d_in, const int* in_sizes, int n_in,
                              void* d_out, int out_size, void* d_ws, size_t ws_size,
                              hipStream_t stream) {
    const float* voltage  = (const float*)d_in[0];
    const float* stimulus = (const float*)d_in[1];
    const int*   ntype    = (const int*)d_in[2];
    const int*   edge_idx = (const int*)d_in[3];
    const float* w        = (const float*)d_in[4];
    const float* vrest    = (const float*)d_in[5];
    const float* tau      = (const float*)d_in[6];
    const float* tp       = (const float*)d_in[7];
    float* out = (float*)d_out;

    const int n_nodes = in_sizes[0];
    const int n_edges = in_sizes[4];
    const int* src = edge_idx;
    const int* dst = edge_idx + n_edges;

    const int B = 256;
    const int G = n_edges / 4;
    int nblk = (G + GPB - 1) / GPB;
    if (nblk < 1) nblk = 1;
    const int nb = (n_nodes + BSIZE - 1) / BSIZE;

    auto align256 = [](size_t x) { return (x + 255) & ~(size_t)255; };

    // per-bucket capacity: mean load (65536) + slack. Pad-to-4 adds ~1.5
    // rec/run * nblk(977) ~= 1.5K/bucket; remaining slack covers >8 sigma
    // of binomial spread (sigma ~= 255). Pick the largest slack that fits.
    int base_cap = (int)(((long long)n_edges * BSIZE) / (long long)(n_nodes > 0 ? n_nodes : 1));
    const int slacks[3] = {4096, 3072, 2048};
    int cap = 0;
    size_t g_off = 0, gcur_off = 0, spill_off = 0, bb_off = 0, need = (size_t)-1;
    for (int si = 0; si < 3; si++) {
        int c = (base_cap + slacks[si] + 3) & ~3;
        size_t go  = 0;
        size_t gc  = align256(go + (size_t)n_nodes * 4);
        size_t sp  = align256(gc + (size_t)(nb + 1) * 4);
        size_t bb  = align256(sp + (size_t)SPILL_CAP * 8);
        size_t nd  = align256(bb + (size_t)nb * (size_t)c * 4);
        if (nd <= ws_size) {
            cap = c; g_off = go; gcur_off = gc; spill_off = sp; bb_off = bb; need = nd;
            break;
        }
    }

    if (nb < NBMAX && cap > 0 && need <= ws_size) {
        float*    g         = (float*)((char*)d_ws + g_off);
        unsigned* gcur      = (unsigned*)((char*)d_ws + gcur_off);
        uint2*    spill     = (uint2*)((char*)d_ws + spill_off);
        unsigned* bucketbuf = (unsigned*)((char*)d_ws + bb_off);

        pre_g_kernel<<<(n_nodes + B - 1) / B, B, 0, stream>>>(
            voltage, ntype, tp, g, gcur, n_nodes, nb);
        scatter_kernel<<<nblk, 1024, 0, stream>>>(
            src, dst, w, g, bucketbuf, gcur, spill, G, n_edges, nblk, nb, cap);
        accum_kernel<<<nb, 1024, 0, stream>>>(
            bucketbuf, gcur, spill, voltage, stimulus, vrest, tau, out,
            n_nodes, nb, cap);
    } else {
        float* g   = (float*)d_ws;
        float* msg = (float*)d_ws + n_nodes;
        node_pre_kernel<<<(n_nodes + B - 1) / B, B, 0, stream>>>(
            voltage, ntype, tp, g, msg, n_nodes);
        if (G > 0)
            edge_scatter_kernel<<<(G + B - 1) / B, B, 0, stream>>>(
                src, dst, w, g, msg, G);
        if (G * 4 < n_edges) {
            int rem = n_edges - G * 4;
            edge_scatter_tail<<<(rem + B - 1) / B, B, 0, stream>>>(
                src, dst, w, g, msg, G * 4, n_edges);
        }
        node_post_kernel<<<(n_nodes + B - 1) / B, B, 0, stream>>>(
            voltage, msg, stimulus, vrest, tau, out, n_nodes);
    }
}